// Round 12
// baseline (131.274 us; speedup 1.0000x reference)
//
#include <hip/hip_runtime.h>
#include <hip/hip_bf16.h>
#include <math.h>

#define BB 4
#define NN 4096
#define MM 32
#define FF 64
#define NM (NN*MM)           // 131072 edges per batch
#define NEDGE (BB*NM)        // 524288
#define NNODE (BB*NN)        // 16384
#define AU_SIZE (NNODE*FF)   // 1048576

typedef __attribute__((ext_vector_type(8))) short bf16x8;
typedef __attribute__((ext_vector_type(4))) float f32x4;

static __device__ __forceinline__ unsigned short f2bf(float x) {
  unsigned int u = __builtin_bit_cast(unsigned int, x);
  unsigned int r = (u + 0x7fffu + ((u >> 16) & 1u)) >> 16;
  return (unsigned short)r;
}
static __device__ __forceinline__ float bf2f(unsigned short h) {
  unsigned int u = ((unsigned int)h) << 16;
  return __builtin_bit_cast(float, u);
}
static __device__ __forceinline__ float tanh_fast(float x) {
  float ex = __expf(2.0f * x);
  return 1.0f - 2.0f * __builtin_amdgcn_rcpf(ex + 1.0f);
}
static __device__ __forceinline__ float readlane_f(float v, int lane) {
  return __builtin_bit_cast(float,
           __builtin_amdgcn_readlane(__builtin_bit_cast(int, v), lane));
}

// ---------------- front: norm stream (blocks 0..2047) + LDS histogram (blocks 2048..2111) ----------------
__global__ __launch_bounds__(256) void k_front(
    const float* __restrict__ bond, const int* __restrict__ tup,
    float* __restrict__ inv, int* __restrict__ part)
{
  __shared__ int lh[8192];   // 32 KB; only used by hist blocks
  if (blockIdx.x < 2048) {
    const int l   = threadIdx.x & 63;
    const int wid = (blockIdx.x*256 + threadIdx.x) >> 6;
    const int nw  = 2048*4;
    for (int r0 = wid*4; r0 < NEDGE; r0 += nw*4) {
      const int row = r0 + (l>>4);
      float4 v = *(const float4*)(bond + (size_t)row*64 + (l&15)*4);
      float s = fmaf(v.x,v.x, fmaf(v.y,v.y, fmaf(v.z,v.z, v.w*v.w)));
      s += __shfl_xor(s, 1); s += __shfl_xor(s, 2);
      s += __shfl_xor(s, 4); s += __shfl_xor(s, 8);
      if ((l&15) == 0) inv[row] = 1.0f/s;      // (s^0.5)^-2 == 1/s
    }
  } else {
    const int bh = blockIdx.x - 2048;          // [0,64)
    #pragma unroll
    for (int j = threadIdx.x; j < 8192; j += 256) lh[j] = 0;
    __syncthreads();
    const int base = bh * 8192;
    #pragma unroll 4
    for (int k = 0; k < 32; ++k) {
      int i = base + k*256 + threadIdx.x;
      int2 t01 = *(const int2*)(tup + (size_t)i*2);
      atomicAdd(&lh[t01.x], 1);
      atomicAdd(&lh[4096 + t01.y], 1);
    }
    __syncthreads();
    int* pp = part + bh*8192;
    #pragma unroll
    for (int j = threadIdx.x; j < 8192; j += 256) pp[j] = lh[j];
  }
}

// ---------------- nodeh: node tiles (blocks 0..1023) + histsum (blocks 1024..1151) ----------------
__global__ __launch_bounds__(256) void k_nodeh(
    const float* __restrict__ atom, const float* __restrict__ inv,
    const int* __restrict__ adj, const float* __restrict__ Wn,
    const float* __restrict__ bn, float* __restrict__ au,
    const int* __restrict__ part, int* __restrict__ cnt,
    float* __restrict__ colsum)
{
  __shared__ float sp[16][65];               // stride 65: 2-way conflicts only (free)
  if (blockIdx.x >= 1024) {
    // histsum part: cnt[h*NNODE + b*4096 + n]
    int i = (blockIdx.x - 1024)*256 + threadIdx.x;   // [0, 32768)
    if (i < BB*128) colsum[i] = 0.f;
    const int h = i >> 14;
    const int b = (i >> 12) & 3;
    const int n = i & 4095;
    int s = 0;
    #pragma unroll
    for (int jj = 0; jj < 16; ++jj)
      s += part[(size_t)(b*16 + jj)*8192 + h*4096 + n];
    cnt[i] = s;
    return;
  }
  const int l  = threadIdx.x & 63;
  const int w  = threadIdx.x >> 6;
  const int n0 = blockIdx.x * 16;            // GLOBAL node id of tile start
  const int b  = n0 >> 12;
  const float* atomB = atom + (size_t)b*NN*FF;   // for local-index gathers only

  #pragma unroll
  for (int k = 0; k < 4; ++k) {
    const int nit  = w*4 + k;
    const int node = n0 + nit;               // global node id
    float invv = inv[(size_t)node*MM + (l & 31)];
    int   idxv = adj[(size_t)node*MM + (l & 31)];
    float wsum = invv;
    #pragma unroll
    for (int off = 1; off <= 16; off <<= 1) wsum += __shfl_xor(wsum, off);
    float acc = 0.f;
    #pragma unroll
    for (int m = 0; m < MM; ++m) {
      int   idx = __builtin_amdgcn_readlane(idxv, m);   // adj[m] (local, [0,NN))
      float wv  = readlane_f(invv, m);                  // inv[m]
      float a   = atomB[(size_t)idx*FF + l];
      acc = fmaf(wv, sqrtf(fabsf(a)), acc);
    }
    float own = sqrtf(fabsf(atom[(size_t)node*FF + l]));   // global index
    sp[nit][l] = own * acc / fmaxf(wsum, 1e-12f);
  }
  __syncthreads();

  const int er = l & 15;
  const int g  = l >> 4;
  const int col = w*16 + er;
  bf16x8 wh[2], wl[2];
  #pragma unroll
  for (int kk = 0; kk < 2; ++kk)
    #pragma unroll
    for (int j = 0; j < 8; ++j) {
      float wv = Wn[(kk*32 + g*8 + j)*64 + col];
      unsigned short h = f2bf(wv);
      wh[kk][j] = (short)h;
      wl[kk][j] = (short)f2bf(wv - bf2f(h));
    }
  bf16x8 ah[2], al[2];
  #pragma unroll
  for (int kk = 0; kk < 2; ++kk) {
    const int f0 = kk*32 + g*8;
    #pragma unroll
    for (int j = 0; j < 8; ++j) {
      float v = sp[er][f0 + j];
      unsigned short h = f2bf(v);
      ah[kk][j] = (short)h;
      al[kk][j] = (short)f2bf(v - bf2f(h));
    }
  }
  float bias = bn[col];
  f32x4 acc;
  acc[0]=bias; acc[1]=bias; acc[2]=bias; acc[3]=bias;
  acc = __builtin_amdgcn_mfma_f32_16x16x32_bf16(ah[0], wh[0], acc, 0,0,0);
  acc = __builtin_amdgcn_mfma_f32_16x16x32_bf16(ah[1], wh[1], acc, 0,0,0);
  acc = __builtin_amdgcn_mfma_f32_16x16x32_bf16(al[0], wh[0], acc, 0,0,0);
  acc = __builtin_amdgcn_mfma_f32_16x16x32_bf16(al[1], wh[1], acc, 0,0,0);
  acc = __builtin_amdgcn_mfma_f32_16x16x32_bf16(ah[0], wl[0], acc, 0,0,0);
  acc = __builtin_amdgcn_mfma_f32_16x16x32_bf16(ah[1], wl[1], acc, 0,0,0);
  #pragma unroll
  for (int r = 0; r < 4; ++r)
    au[(size_t)(n0 + g*4 + r)*64 + col] = fmaxf(acc[r], 0.f);
}

// ---------------- column L1 sums ----------------
__global__ __launch_bounds__(128) void k_colsum(
    const float* __restrict__ au, const int* __restrict__ cnt,
    float* __restrict__ colsum)
{
  int c  = threadIdx.x;            // 0..127
  int b  = blockIdx.x >> 7;
  int ch = blockIdx.x & 127;
  int f  = c & 63;
  const int*   cp = cnt + ((c >> 6) ? NNODE : 0) + (b<<12);
  const float* ab = au + ((size_t)(b<<12))*64;
  float acc = 0.f;
  int n0 = ch*32;
  for (int n = n0; n < n0+32; ++n)
    acc += (float)cp[n] * ab[(size_t)n*64 + f];
  atomicAdd(&colsum[b*128 + c], acc);
}

// ---------------- P0/P1 via MFMA, stored as bf16 ----------------
__global__ __launch_bounds__(256) void k_p01(
    const float* __restrict__ au, const float* __restrict__ colsum,
    const float* __restrict__ Wn2e, const float* __restrict__ bn2e,
    unsigned short* __restrict__ P0, unsigned short* __restrict__ P1)
{
  const int l  = threadIdx.x & 63;
  const int er = l & 15;
  const int g  = l >> 4;
  bf16x8 wt[4][2], wb[4][2];
  #pragma unroll
  for (int t = 0; t < 4; ++t) {
    const int col = t*16 + er;
    #pragma unroll
    for (int kk = 0; kk < 2; ++kk)
      #pragma unroll
      for (int j = 0; j < 8; ++j) {
        const int k = kk*32 + g*8 + j;
        wt[t][kk][j] = (short)f2bf(Wn2e[k*64 + col]);
        wb[t][kk][j] = (short)f2bf(Wn2e[(64 + k)*64 + col]);
      }
  }
  float bias[4];
  #pragma unroll
  for (int t = 0; t < 4; ++t) bias[t] = bn2e[t*16 + er];

  const int wid = (blockIdx.x*256 + threadIdx.x) >> 6;
  const int nw  = gridDim.x * 4;
  for (int tile = wid; tile < NNODE/16; tile += nw) {
    const int n0 = tile*16;
    const int b  = tile >> 8;
    const float* ar_ = au + (size_t)(n0 + er)*64;
    bf16x8 x0[2], x1[2];
    #pragma unroll
    for (int kk = 0; kk < 2; ++kk) {
      const int f0 = kk*32 + g*8;
      float4 a0 = *(const float4*)(ar_ + f0);
      float4 a1 = *(const float4*)(ar_ + f0 + 4);
      float4 c0 = *(const float4*)(colsum + b*128 + f0);
      float4 c1 = *(const float4*)(colsum + b*128 + f0 + 4);
      float4 d0 = *(const float4*)(colsum + b*128 + 64 + f0);
      float4 d1 = *(const float4*)(colsum + b*128 + 64 + f0 + 4);
      float v[8] = {a0.x,a0.y,a0.z,a0.w,a1.x,a1.y,a1.z,a1.w};
      float c[8] = {c0.x,c0.y,c0.z,c0.w,c1.x,c1.y,c1.z,c1.w};
      float d[8] = {d0.x,d0.y,d0.z,d0.w,d1.x,d1.y,d1.z,d1.w};
      #pragma unroll
      for (int j = 0; j < 8; ++j) {
        x0[kk][j] = (short)f2bf(v[j] * __builtin_amdgcn_rcpf(fmaxf(c[j], 1e-12f)));
        x1[kk][j] = (short)f2bf(v[j] * __builtin_amdgcn_rcpf(fmaxf(d[j], 1e-12f)));
      }
    }
    f32x4 p0[4], p1[4];
    #pragma unroll
    for (int t = 0; t < 4; ++t) {
      p0[t][0]=bias[t]; p0[t][1]=bias[t]; p0[t][2]=bias[t]; p0[t][3]=bias[t];
      p1[t][0]=0.f; p1[t][1]=0.f; p1[t][2]=0.f; p1[t][3]=0.f;
      p0[t] = __builtin_amdgcn_mfma_f32_16x16x32_bf16(x0[0], wt[t][0], p0[t], 0,0,0);
      p0[t] = __builtin_amdgcn_mfma_f32_16x16x32_bf16(x0[1], wt[t][1], p0[t], 0,0,0);
      p1[t] = __builtin_amdgcn_mfma_f32_16x16x32_bf16(x1[0], wb[t][0], p1[t], 0,0,0);
      p1[t] = __builtin_amdgcn_mfma_f32_16x16x32_bf16(x1[1], wb[t][1], p1[t], 0,0,0);
    }
    #pragma unroll
    for (int t = 0; t < 4; ++t)
      #pragma unroll
      for (int r = 0; r < 4; ++r) {
        P0[(size_t)(n0 + g*4 + r)*64 + t*16 + er] = f2bf(p0[t][r]);
        P1[(size_t)(n0 + g*4 + r)*64 + t*16 + er] = f2bf(p1[t][r]);
      }
  }
}

// ---------------- per-edge via MFMA: bf16 P gathers, grid-stride, tup prefetch ----------------
__global__ __launch_bounds__(256) void k_edge_mfma(
    const float* __restrict__ bond, const int* __restrict__ tup,
    const unsigned short* __restrict__ P0, const unsigned short* __restrict__ P1,
    const float* __restrict__ We, const float* __restrict__ be,
    float* __restrict__ outB)
{
  const int l  = threadIdx.x & 63;
  const int er = l & 15;
  const int g  = l >> 4;
  bf16x8 wh[4][2];
  #pragma unroll
  for (int t = 0; t < 4; ++t)
    #pragma unroll
    for (int kk = 0; kk < 2; ++kk)
      #pragma unroll
      for (int j = 0; j < 8; ++j)
        wh[t][kk][j] = (short)f2bf(We[(kk*32 + g*8 + j)*64 + t*16 + er]);
  float bias[4];
  #pragma unroll
  for (int t = 0; t < 4; ++t) bias[t] = be[t*16 + er];

  const int nw  = gridDim.x * 4;
  const int ntiles = NEDGE/16;
  int tile = (blockIdx.x*256 + threadIdx.x) >> 6;
  if (tile >= ntiles) return;
  int2 tt = *(const int2*)(tup + (size_t)(tile*16 + er)*2);
  while (tile < ntiles) {
    const int next = tile + nw;
    int2 ttn = tt;
    if (next < ntiles) ttn = *(const int2*)(tup + (size_t)(next*16 + er)*2);

    const int e0 = tile*16;
    const int b  = e0 >> 17;
    const unsigned short* p0r = P0 + ((size_t)((b<<12) + tt.x))*64;
    const unsigned short* p1r = P1 + ((size_t)((b<<12) + tt.y))*64;
    const float* br = bond + (size_t)(e0 + er)*64;

    bf16x8 ah[2];
    #pragma unroll
    for (int kk = 0; kk < 2; ++kk) {
      const int f0 = kk*32 + g*8;
      float4 b0 = *(const float4*)(br + f0);
      float4 b1 = *(const float4*)(br + f0 + 4);
      bf16x8 q = *(const bf16x8*)(p0r + f0);
      bf16x8 r = *(const bf16x8*)(p1r + f0);
      float bb[8] = {b0.x,b0.y,b0.z,b0.w,b1.x,b1.y,b1.z,b1.w};
      #pragma unroll
      for (int j = 0; j < 8; ++j) {
        float p = bf2f((unsigned short)q[j]) + bf2f((unsigned short)r[j]);
        ah[kk][j] = (short)f2bf(bb[j] + tanh_fast(p));
      }
    }

    f32x4 acc[4];
    #pragma unroll
    for (int t = 0; t < 4; ++t) {
      acc[t][0]=bias[t]; acc[t][1]=bias[t]; acc[t][2]=bias[t]; acc[t][3]=bias[t];
      acc[t] = __builtin_amdgcn_mfma_f32_16x16x32_bf16(ah[0], wh[t][0], acc[t], 0,0,0);
      acc[t] = __builtin_amdgcn_mfma_f32_16x16x32_bf16(ah[1], wh[t][1], acc[t], 0,0,0);
    }

    float* orow = outB + (size_t)e0*64;
    #pragma unroll
    for (int t = 0; t < 4; ++t)
      #pragma unroll
      for (int r = 0; r < 4; ++r)
        orow[(size_t)(g*4 + r)*64 + t*16 + er] = acc[t][r];

    tile = next; tt = ttn;
  }
}

extern "C" void kernel_launch(void* const* d_in, const int* in_sizes, int n_in,
                              void* d_out, int out_size, void* d_ws, size_t ws_size,
                              hipStream_t stream)
{
  (void)in_sizes; (void)n_in; (void)out_size; (void)ws_size;
  const float* atom = (const float*)d_in[0];
  const float* bond = (const float*)d_in[1];
  const int*   adj  = (const int*)d_in[2];
  const int*   tup  = (const int*)d_in[3];
  const float* Wn   = (const float*)d_in[4];
  const float* We   = (const float*)d_in[5];
  const float* Wn2e = (const float*)d_in[6];
  const float* bn   = (const float*)d_in[7];
  const float* be   = (const float*)d_in[8];
  const float* bn2e = (const float*)d_in[9];

  float* au   = (float*)d_out;             // output 0: (B,N,64)
  float* outB = (float*)d_out + AU_SIZE;   // output 1: (B,N,M,64)

  char* ws = (char*)d_ws;
  int*            cnt    = (int*)ws;                         // @0       128 KB
  float*          colsum = (float*)(ws + 0x20000);           // @128K    2 KB
  float*          inv    = (float*)(ws + 0x40000);           // @256K    2 MB
  unsigned short* P0     = (unsigned short*)(ws + 0x240000); // @2.25M   2 MB
  unsigned short* P1     = (unsigned short*)(ws + 0x440000); // @4.25M   2 MB
  int*            part   = (int*)(ws + 0x640000);            // @6.25M   2 MB

  hipLaunchKernelGGL(k_front,     dim3(2112),     dim3(256), 0, stream, bond, tup, inv, part);
  hipLaunchKernelGGL(k_nodeh,     dim3(1152),     dim3(256), 0, stream, atom, inv, adj, Wn, bn, au, part, cnt, colsum);
  hipLaunchKernelGGL(k_colsum,    dim3(BB*128),   dim3(128), 0, stream, au, cnt, colsum);
  hipLaunchKernelGGL(k_p01,       dim3(256),      dim3(256), 0, stream, au, colsum, Wn2e, bn2e, P0, P1);
  hipLaunchKernelGGL(k_edge_mfma, dim3(2048),     dim3(256), 0, stream, bond, tup, P0, P1, We, be, outB);
}

// Round 13
// 127.714 us; speedup vs baseline: 1.0279x; 1.0279x over previous
//
#include <hip/hip_runtime.h>
#include <hip/hip_bf16.h>
#include <math.h>

#define BB 4
#define NN 4096
#define MM 32
#define FF 64
#define NM (NN*MM)           // 131072 edges per batch
#define NEDGE (BB*NM)        // 524288
#define NNODE (BB*NN)        // 16384
#define AU_SIZE (NNODE*FF)   // 1048576

typedef __attribute__((ext_vector_type(8))) short bf16x8;
typedef __attribute__((ext_vector_type(4))) float f32x4;

static __device__ __forceinline__ unsigned short f2bf(float x) {
  unsigned int u = __builtin_bit_cast(unsigned int, x);
  unsigned int r = (u + 0x7fffu + ((u >> 16) & 1u)) >> 16;
  return (unsigned short)r;
}
static __device__ __forceinline__ float bf2f(unsigned short h) {
  unsigned int u = ((unsigned int)h) << 16;
  return __builtin_bit_cast(float, u);
}
static __device__ __forceinline__ float tanh_fast(float x) {
  float ex = __expf(2.0f * x);
  return 1.0f - 2.0f * __builtin_amdgcn_rcpf(ex + 1.0f);
}
static __device__ __forceinline__ float readlane_f(float v, int lane) {
  return __builtin_bit_cast(float,
           __builtin_amdgcn_readlane(__builtin_bit_cast(int, v), lane));
}

// ---------------- norm: inv[row] = 1/||bond_row||^2  +  emit bond as bf16 ----------------
// wave = 4 rows/iter, 16-lane group per row (1 KB/instr reads, 128 B/row bf16 writes)
__global__ __launch_bounds__(256) void k_norm(
    const float* __restrict__ bond, float* __restrict__ inv,
    unsigned short* __restrict__ bondh)
{
  const int l   = threadIdx.x & 63;
  const int wid = (blockIdx.x*256 + threadIdx.x) >> 6;
  const int nw  = gridDim.x*4;
  for (int r0 = wid*4; r0 < NEDGE; r0 += nw*4) {
    const int row = r0 + (l>>4);
    float4 v = *(const float4*)(bond + (size_t)row*64 + (l&15)*4);
    // bf16 copy (consumed by k_edge from L3)
    ushort4 h;
    h.x = f2bf(v.x); h.y = f2bf(v.y); h.z = f2bf(v.z); h.w = f2bf(v.w);
    *(ushort4*)(bondh + (size_t)row*64 + (l&15)*4) = h;
    float s = fmaf(v.x,v.x, fmaf(v.y,v.y, fmaf(v.z,v.z, v.w*v.w)));
    s += __shfl_xor(s, 1); s += __shfl_xor(s, 2);
    s += __shfl_xor(s, 4); s += __shfl_xor(s, 8);
    if ((l&15) == 0) inv[row] = 1.0f/s;      // (s^0.5)^-2 == 1/s
  }
}

// ---------------- hierarchical histogram: LDS atomics + partial stores ----------------
__global__ __launch_bounds__(256) void k_hist_lds(
    const int* __restrict__ tup, int* __restrict__ part)
{
  __shared__ int lh[8192];   // 2 histograms x 4096 bins = 32 KB
  #pragma unroll
  for (int j = threadIdx.x; j < 8192; j += 256) lh[j] = 0;
  __syncthreads();
  const int base = blockIdx.x * 8192;
  #pragma unroll 4
  for (int k = 0; k < 32; ++k) {
    int i = base + k*256 + threadIdx.x;
    int2 t01 = *(const int2*)(tup + (size_t)i*2);
    atomicAdd(&lh[t01.x], 1);
    atomicAdd(&lh[4096 + t01.y], 1);
  }
  __syncthreads();
  int* pp = part + blockIdx.x*8192;
  #pragma unroll
  for (int j = threadIdx.x; j < 8192; j += 256) pp[j] = lh[j];
}

// ---------------- sum partials -> cnt ; also zero colsum ----------------
__global__ __launch_bounds__(256) void k_histsum(
    const int* __restrict__ part, int* __restrict__ cnt,
    float* __restrict__ colsum)
{
  int i = blockIdx.x*256 + threadIdx.x;     // [0, 32768)
  if (i < BB*128) colsum[i] = 0.f;
  const int h = i >> 14;
  const int b = (i >> 12) & 3;
  const int n = i & 4095;
  int s = 0;
  #pragma unroll
  for (int jj = 0; jj < 16; ++jj)
    s += part[(size_t)(b*16 + jj)*8192 + h*4096 + n];
  cnt[i] = s;
}

// ---------------- node: gather-average (sqrt on the fly) -> LDS -> au MFMA ----------------
__global__ __launch_bounds__(256) void k_node(
    const float* __restrict__ atom, const float* __restrict__ inv,
    const int* __restrict__ adj, const float* __restrict__ Wn,
    const float* __restrict__ bn, float* __restrict__ au)
{
  __shared__ float sp[16][65];               // stride 65: 2-way conflicts only (free)
  const int l  = threadIdx.x & 63;
  const int w  = threadIdx.x >> 6;
  const int n0 = blockIdx.x * 16;            // GLOBAL node id of tile start
  const int b  = n0 >> 12;
  const float* atomB = atom + (size_t)b*NN*FF;   // for local-index gathers only

  #pragma unroll
  for (int k = 0; k < 4; ++k) {
    const int nit  = w*4 + k;
    const int node = n0 + nit;               // global node id
    float invv = inv[(size_t)node*MM + (l & 31)];
    int   idxv = adj[(size_t)node*MM + (l & 31)];
    float wsum = invv;
    #pragma unroll
    for (int off = 1; off <= 16; off <<= 1) wsum += __shfl_xor(wsum, off);
    float acc = 0.f;
    #pragma unroll
    for (int m = 0; m < MM; ++m) {
      int   idx = __builtin_amdgcn_readlane(idxv, m);   // adj[m] (local, [0,NN))
      float wv  = readlane_f(invv, m);                  // inv[m]
      float a   = atomB[(size_t)idx*FF + l];
      acc = fmaf(wv, sqrtf(fabsf(a)), acc);
    }
    float own = sqrtf(fabsf(atom[(size_t)node*FF + l]));   // global index
    sp[nit][l] = own * acc / fmaxf(wsum, 1e-12f);
  }
  __syncthreads();

  const int er = l & 15;
  const int g  = l >> 4;
  const int col = w*16 + er;
  bf16x8 wh[2], wl[2];
  #pragma unroll
  for (int kk = 0; kk < 2; ++kk)
    #pragma unroll
    for (int j = 0; j < 8; ++j) {
      float wv = Wn[(kk*32 + g*8 + j)*64 + col];
      unsigned short h = f2bf(wv);
      wh[kk][j] = (short)h;
      wl[kk][j] = (short)f2bf(wv - bf2f(h));
    }
  bf16x8 ah[2], al[2];
  #pragma unroll
  for (int kk = 0; kk < 2; ++kk) {
    const int f0 = kk*32 + g*8;
    #pragma unroll
    for (int j = 0; j < 8; ++j) {
      float v = sp[er][f0 + j];
      unsigned short h = f2bf(v);
      ah[kk][j] = (short)h;
      al[kk][j] = (short)f2bf(v - bf2f(h));
    }
  }
  float bias = bn[col];
  f32x4 acc;
  acc[0]=bias; acc[1]=bias; acc[2]=bias; acc[3]=bias;
  acc = __builtin_amdgcn_mfma_f32_16x16x32_bf16(ah[0], wh[0], acc, 0,0,0);
  acc = __builtin_amdgcn_mfma_f32_16x16x32_bf16(ah[1], wh[1], acc, 0,0,0);
  acc = __builtin_amdgcn_mfma_f32_16x16x32_bf16(al[0], wh[0], acc, 0,0,0);
  acc = __builtin_amdgcn_mfma_f32_16x16x32_bf16(al[1], wh[1], acc, 0,0,0);
  acc = __builtin_amdgcn_mfma_f32_16x16x32_bf16(ah[0], wl[0], acc, 0,0,0);
  acc = __builtin_amdgcn_mfma_f32_16x16x32_bf16(ah[1], wl[1], acc, 0,0,0);
  #pragma unroll
  for (int r = 0; r < 4; ++r)
    au[(size_t)(n0 + g*4 + r)*64 + col] = fmaxf(acc[r], 0.f);
}

// ---------------- column L1 sums ----------------
__global__ __launch_bounds__(128) void k_colsum(
    const float* __restrict__ au, const int* __restrict__ cnt,
    float* __restrict__ colsum)
{
  int c  = threadIdx.x;            // 0..127
  int b  = blockIdx.x >> 7;
  int ch = blockIdx.x & 127;
  int f  = c & 63;
  const int*   cp = cnt + ((c >> 6) ? NNODE : 0) + (b<<12);
  const float* ab = au + ((size_t)(b<<12))*64;
  float acc = 0.f;
  int n0 = ch*32;
  for (int n = n0; n < n0+32; ++n)
    acc += (float)cp[n] * ab[(size_t)n*64 + f];
  atomicAdd(&colsum[b*128 + c], acc);
}

// ---------------- P0/P1 via MFMA, stored as bf16 ----------------
__global__ __launch_bounds__(256) void k_p01(
    const float* __restrict__ au, const float* __restrict__ colsum,
    const float* __restrict__ Wn2e, const float* __restrict__ bn2e,
    unsigned short* __restrict__ P0, unsigned short* __restrict__ P1)
{
  const int l  = threadIdx.x & 63;
  const int er = l & 15;
  const int g  = l >> 4;
  bf16x8 wt[4][2], wb[4][2];
  #pragma unroll
  for (int t = 0; t < 4; ++t) {
    const int col = t*16 + er;
    #pragma unroll
    for (int kk = 0; kk < 2; ++kk)
      #pragma unroll
      for (int j = 0; j < 8; ++j) {
        const int k = kk*32 + g*8 + j;
        wt[t][kk][j] = (short)f2bf(Wn2e[k*64 + col]);
        wb[t][kk][j] = (short)f2bf(Wn2e[(64 + k)*64 + col]);
      }
  }
  float bias[4];
  #pragma unroll
  for (int t = 0; t < 4; ++t) bias[t] = bn2e[t*16 + er];

  const int wid = (blockIdx.x*256 + threadIdx.x) >> 6;
  const int nw  = gridDim.x * 4;
  for (int tile = wid; tile < NNODE/16; tile += nw) {
    const int n0 = tile*16;
    const int b  = tile >> 8;
    const float* ar_ = au + (size_t)(n0 + er)*64;
    bf16x8 x0[2], x1[2];
    #pragma unroll
    for (int kk = 0; kk < 2; ++kk) {
      const int f0 = kk*32 + g*8;
      float4 a0 = *(const float4*)(ar_ + f0);
      float4 a1 = *(const float4*)(ar_ + f0 + 4);
      float4 c0 = *(const float4*)(colsum + b*128 + f0);
      float4 c1 = *(const float4*)(colsum + b*128 + f0 + 4);
      float4 d0 = *(const float4*)(colsum + b*128 + 64 + f0);
      float4 d1 = *(const float4*)(colsum + b*128 + 64 + f0 + 4);
      float v[8] = {a0.x,a0.y,a0.z,a0.w,a1.x,a1.y,a1.z,a1.w};
      float c[8] = {c0.x,c0.y,c0.z,c0.w,c1.x,c1.y,c1.z,c1.w};
      float d[8] = {d0.x,d0.y,d0.z,d0.w,d1.x,d1.y,d1.z,d1.w};
      #pragma unroll
      for (int j = 0; j < 8; ++j) {
        x0[kk][j] = (short)f2bf(v[j] * __builtin_amdgcn_rcpf(fmaxf(c[j], 1e-12f)));
        x1[kk][j] = (short)f2bf(v[j] * __builtin_amdgcn_rcpf(fmaxf(d[j], 1e-12f)));
      }
    }
    f32x4 p0[4], p1[4];
    #pragma unroll
    for (int t = 0; t < 4; ++t) {
      p0[t][0]=bias[t]; p0[t][1]=bias[t]; p0[t][2]=bias[t]; p0[t][3]=bias[t];
      p1[t][0]=0.f; p1[t][1]=0.f; p1[t][2]=0.f; p1[t][3]=0.f;
      p0[t] = __builtin_amdgcn_mfma_f32_16x16x32_bf16(x0[0], wt[t][0], p0[t], 0,0,0);
      p0[t] = __builtin_amdgcn_mfma_f32_16x16x32_bf16(x0[1], wt[t][1], p0[t], 0,0,0);
      p1[t] = __builtin_amdgcn_mfma_f32_16x16x32_bf16(x1[0], wb[t][0], p1[t], 0,0,0);
      p1[t] = __builtin_amdgcn_mfma_f32_16x16x32_bf16(x1[1], wb[t][1], p1[t], 0,0,0);
    }
    #pragma unroll
    for (int t = 0; t < 4; ++t)
      #pragma unroll
      for (int r = 0; r < 4; ++r) {
        P0[(size_t)(n0 + g*4 + r)*64 + t*16 + er] = f2bf(p0[t][r]);
        P1[(size_t)(n0 + g*4 + r)*64 + t*16 + er] = f2bf(p1[t][r]);
      }
  }
}

// ---------------- per-edge via MFMA: bf16 bond (L3-hot) + bf16 P gathers + NT stores ----------------
__global__ __launch_bounds__(256) void k_edge_mfma(
    const unsigned short* __restrict__ bondh, const int* __restrict__ tup,
    const unsigned short* __restrict__ P0, const unsigned short* __restrict__ P1,
    const float* __restrict__ We, const float* __restrict__ be,
    float* __restrict__ outB)
{
  const int l  = threadIdx.x & 63;
  const int er = l & 15;
  const int g  = l >> 4;
  bf16x8 wh[4][2];
  #pragma unroll
  for (int t = 0; t < 4; ++t)
    #pragma unroll
    for (int kk = 0; kk < 2; ++kk)
      #pragma unroll
      for (int j = 0; j < 8; ++j)
        wh[t][kk][j] = (short)f2bf(We[(kk*32 + g*8 + j)*64 + t*16 + er]);
  float bias[4];
  #pragma unroll
  for (int t = 0; t < 4; ++t) bias[t] = be[t*16 + er];

  const int nw  = gridDim.x * 4;
  const int ntiles = NEDGE/16;
  int tile = (blockIdx.x*256 + threadIdx.x) >> 6;
  if (tile >= ntiles) return;
  int2 tt = *(const int2*)(tup + (size_t)(tile*16 + er)*2);
  while (tile < ntiles) {
    const int next = tile + nw;
    int2 ttn = tt;
    if (next < ntiles) ttn = *(const int2*)(tup + (size_t)(next*16 + er)*2);

    const int e0 = tile*16;
    const int b  = e0 >> 17;
    const unsigned short* p0r = P0 + ((size_t)((b<<12) + tt.x))*64;
    const unsigned short* p1r = P1 + ((size_t)((b<<12) + tt.y))*64;
    const unsigned short* br  = bondh + (size_t)(e0 + er)*64;

    bf16x8 ah[2];
    #pragma unroll
    for (int kk = 0; kk < 2; ++kk) {
      const int f0 = kk*32 + g*8;
      bf16x8 bv = *(const bf16x8*)(br + f0);
      bf16x8 q  = *(const bf16x8*)(p0r + f0);
      bf16x8 r  = *(const bf16x8*)(p1r + f0);
      #pragma unroll
      for (int j = 0; j < 8; ++j) {
        float p = bf2f((unsigned short)q[j]) + bf2f((unsigned short)r[j]);
        ah[kk][j] = (short)f2bf(bf2f((unsigned short)bv[j]) + tanh_fast(p));
      }
    }

    f32x4 acc[4];
    #pragma unroll
    for (int t = 0; t < 4; ++t) {
      acc[t][0]=bias[t]; acc[t][1]=bias[t]; acc[t][2]=bias[t]; acc[t][3]=bias[t];
      acc[t] = __builtin_amdgcn_mfma_f32_16x16x32_bf16(ah[0], wh[t][0], acc[t], 0,0,0);
      acc[t] = __builtin_amdgcn_mfma_f32_16x16x32_bf16(ah[1], wh[t][1], acc[t], 0,0,0);
    }

    float* orow = outB + (size_t)e0*64;
    #pragma unroll
    for (int t = 0; t < 4; ++t)
      #pragma unroll
      for (int r = 0; r < 4; ++r)
        __builtin_nontemporal_store(acc[t][r],
            &orow[(size_t)(g*4 + r)*64 + t*16 + er]);

    tile = next; tt = ttn;
  }
}

extern "C" void kernel_launch(void* const* d_in, const int* in_sizes, int n_in,
                              void* d_out, int out_size, void* d_ws, size_t ws_size,
                              hipStream_t stream)
{
  (void)in_sizes; (void)n_in; (void)out_size; (void)ws_size;
  const float* atom = (const float*)d_in[0];
  const float* bond = (const float*)d_in[1];
  const int*   adj  = (const int*)d_in[2];
  const int*   tup  = (const int*)d_in[3];
  const float* Wn   = (const float*)d_in[4];
  const float* We   = (const float*)d_in[5];
  const float* Wn2e = (const float*)d_in[6];
  const float* bn   = (const float*)d_in[7];
  const float* be   = (const float*)d_in[8];
  const float* bn2e = (const float*)d_in[9];

  float* au   = (float*)d_out;             // output 0: (B,N,64)
  float* outB = (float*)d_out + AU_SIZE;   // output 1: (B,N,M,64)

  char* ws = (char*)d_ws;
  int*            cnt    = (int*)ws;                         // @0       128 KB
  float*          colsum = (float*)(ws + 0x20000);           // @128K    2 KB
  float*          inv    = (float*)(ws + 0x40000);           // @256K    2 MB
  unsigned short* P0     = (unsigned short*)(ws + 0x240000); // @2.25M   2 MB
  unsigned short* P1     = (unsigned short*)(ws + 0x440000); // @4.25M   2 MB
  int*            part   = (int*)(ws + 0x640000);            // @6.25M   2 MB
  unsigned short* bondh  = (unsigned short*)(ws + 0x1000000);// @16M     64 MB

  hipLaunchKernelGGL(k_norm,      dim3(2048),     dim3(256), 0, stream, bond, inv, bondh);
  hipLaunchKernelGGL(k_hist_lds,  dim3(64),       dim3(256), 0, stream, tup, part);
  hipLaunchKernelGGL(k_histsum,   dim3(128),      dim3(256), 0, stream, part, cnt, colsum);
  hipLaunchKernelGGL(k_node,      dim3(NNODE/16), dim3(256), 0, stream, atom, inv, adj, Wn, bn, au);
  hipLaunchKernelGGL(k_colsum,    dim3(BB*128),   dim3(128), 0, stream, au, cnt, colsum);
  hipLaunchKernelGGL(k_p01,       dim3(256),      dim3(256), 0, stream, au, colsum, Wn2e, bn2e, P0, P1);
  hipLaunchKernelGGL(k_edge_mfma, dim3(2048),     dim3(256), 0, stream, bondh, tup, P0, P1, We, be, outB);
}

// Round 15
// 124.593 us; speedup vs baseline: 1.0536x; 1.0251x over previous
//
#include <hip/hip_runtime.h>
#include <hip/hip_bf16.h>
#include <math.h>

#define BB 4
#define NN 4096
#define MM 32
#define FF 64
#define NM (NN*MM)           // 131072 edges per batch
#define NEDGE (BB*NM)        // 524288
#define NNODE (BB*NN)        // 16384
#define AU_SIZE (NNODE*FF)   // 1048576

typedef __attribute__((ext_vector_type(8))) short bf16x8;
typedef __attribute__((ext_vector_type(4))) float f32x4;

static __device__ __forceinline__ unsigned short f2bf(float x) {
  unsigned int u = __builtin_bit_cast(unsigned int, x);
  unsigned int r = (u + 0x7fffu + ((u >> 16) & 1u)) >> 16;
  return (unsigned short)r;
}
static __device__ __forceinline__ float bf2f(unsigned short h) {
  unsigned int u = ((unsigned int)h) << 16;
  return __builtin_bit_cast(float, u);
}
static __device__ __forceinline__ float tanh_fast(float x) {
  float ex = __expf(2.0f * x);
  return 1.0f - 2.0f * __builtin_amdgcn_rcpf(ex + 1.0f);
}
static __device__ __forceinline__ float readlane_f(float v, int lane) {
  return __builtin_bit_cast(float,
           __builtin_amdgcn_readlane(__builtin_bit_cast(int, v), lane));
}

// ---------------- norm: inv[row] = 1/||bond_row||^2  +  emit bond as bf16 ----------------
__global__ __launch_bounds__(256) void k_norm(
    const float* __restrict__ bond, float* __restrict__ inv,
    unsigned short* __restrict__ bondh)
{
  const int l   = threadIdx.x & 63;
  const int wid = (blockIdx.x*256 + threadIdx.x) >> 6;
  const int nw  = gridDim.x*4;
  for (int r0 = wid*4; r0 < NEDGE; r0 += nw*4) {
    const int row = r0 + (l>>4);
    float4 v = *(const float4*)(bond + (size_t)row*64 + (l&15)*4);
    ushort4 h;
    h.x = f2bf(v.x); h.y = f2bf(v.y); h.z = f2bf(v.z); h.w = f2bf(v.w);
    *(ushort4*)(bondh + (size_t)row*64 + (l&15)*4) = h;
    float s = fmaf(v.x,v.x, fmaf(v.y,v.y, fmaf(v.z,v.z, v.w*v.w)));
    s += __shfl_xor(s, 1); s += __shfl_xor(s, 2);
    s += __shfl_xor(s, 4); s += __shfl_xor(s, 8);
    if ((l&15) == 0) inv[row] = 1.0f/s;      // (s^0.5)^-2 == 1/s
  }
}

// ---------------- hierarchical histogram: LDS atomics + partial stores ----------------
__global__ __launch_bounds__(256) void k_hist_lds(
    const int* __restrict__ tup, int* __restrict__ part)
{
  __shared__ int lh[8192];   // 2 histograms x 4096 bins = 32 KB
  #pragma unroll
  for (int j = threadIdx.x; j < 8192; j += 256) lh[j] = 0;
  __syncthreads();
  const int base = blockIdx.x * 8192;
  #pragma unroll 4
  for (int k = 0; k < 32; ++k) {
    int i = base + k*256 + threadIdx.x;
    int2 t01 = *(const int2*)(tup + (size_t)i*2);
    atomicAdd(&lh[t01.x], 1);
    atomicAdd(&lh[4096 + t01.y], 1);
  }
  __syncthreads();
  int* pp = part + blockIdx.x*8192;
  #pragma unroll
  for (int j = threadIdx.x; j < 8192; j += 256) pp[j] = lh[j];
}

// ---------------- sum partials -> cnt ; also zero colsum ----------------
__global__ __launch_bounds__(256) void k_histsum(
    const int* __restrict__ part, int* __restrict__ cnt,
    float* __restrict__ colsum)
{
  int i = blockIdx.x*256 + threadIdx.x;     // [0, 32768)
  if (i < BB*128) colsum[i] = 0.f;
  const int h = i >> 14;
  const int b = (i >> 12) & 3;
  const int n = i & 4095;
  int s = 0;
  #pragma unroll
  for (int jj = 0; jj < 16; ++jj)
    s += part[(size_t)(b*16 + jj)*8192 + h*4096 + n];
  cnt[i] = s;
}

// ---------------- node: gather-average (sqrt on the fly) -> LDS -> au MFMA ----------------
__global__ __launch_bounds__(256) void k_node(
    const float* __restrict__ atom, const float* __restrict__ inv,
    const int* __restrict__ adj, const float* __restrict__ Wn,
    const float* __restrict__ bn, float* __restrict__ au)
{
  __shared__ float sp[16][65];               // stride 65: 2-way conflicts only (free)
  const int l  = threadIdx.x & 63;
  const int w  = threadIdx.x >> 6;
  const int n0 = blockIdx.x * 16;            // GLOBAL node id of tile start
  const int b  = n0 >> 12;
  const float* atomB = atom + (size_t)b*NN*FF;   // for local-index gathers only

  #pragma unroll
  for (int k = 0; k < 4; ++k) {
    const int nit  = w*4 + k;
    const int node = n0 + nit;               // global node id
    float invv = inv[(size_t)node*MM + (l & 31)];
    int   idxv = adj[(size_t)node*MM + (l & 31)];
    float wsum = invv;
    #pragma unroll
    for (int off = 1; off <= 16; off <<= 1) wsum += __shfl_xor(wsum, off);
    float acc = 0.f;
    #pragma unroll
    for (int m = 0; m < MM; ++m) {
      int   idx = __builtin_amdgcn_readlane(idxv, m);   // adj[m] (local, [0,NN))
      float wv  = readlane_f(invv, m);                  // inv[m]
      float a   = atomB[(size_t)idx*FF + l];
      acc = fmaf(wv, sqrtf(fabsf(a)), acc);
    }
    float own = sqrtf(fabsf(atom[(size_t)node*FF + l]));   // global index
    sp[nit][l] = own * acc / fmaxf(wsum, 1e-12f);
  }
  __syncthreads();

  const int er = l & 15;
  const int g  = l >> 4;
  const int col = w*16 + er;
  bf16x8 wh[2], wl[2];
  #pragma unroll
  for (int kk = 0; kk < 2; ++kk)
    #pragma unroll
    for (int j = 0; j < 8; ++j) {
      float wv = Wn[(kk*32 + g*8 + j)*64 + col];
      unsigned short h = f2bf(wv);
      wh[kk][j] = (short)h;
      wl[kk][j] = (short)f2bf(wv - bf2f(h));
    }
  bf16x8 ah[2], al[2];
  #pragma unroll
  for (int kk = 0; kk < 2; ++kk) {
    const int f0 = kk*32 + g*8;
    #pragma unroll
    for (int j = 0; j < 8; ++j) {
      float v = sp[er][f0 + j];
      unsigned short h = f2bf(v);
      ah[kk][j] = (short)h;
      al[kk][j] = (short)f2bf(v - bf2f(h));
    }
  }
  float bias = bn[col];
  f32x4 acc;
  acc[0]=bias; acc[1]=bias; acc[2]=bias; acc[3]=bias;
  acc = __builtin_amdgcn_mfma_f32_16x16x32_bf16(ah[0], wh[0], acc, 0,0,0);
  acc = __builtin_amdgcn_mfma_f32_16x16x32_bf16(ah[1], wh[1], acc, 0,0,0);
  acc = __builtin_amdgcn_mfma_f32_16x16x32_bf16(al[0], wh[0], acc, 0,0,0);
  acc = __builtin_amdgcn_mfma_f32_16x16x32_bf16(al[1], wh[1], acc, 0,0,0);
  acc = __builtin_amdgcn_mfma_f32_16x16x32_bf16(ah[0], wl[0], acc, 0,0,0);
  acc = __builtin_amdgcn_mfma_f32_16x16x32_bf16(ah[1], wl[1], acc, 0,0,0);
  #pragma unroll
  for (int r = 0; r < 4; ++r)
    au[(size_t)(n0 + g*4 + r)*64 + col] = fmaxf(acc[r], 0.f);
}

// ---------------- column L1 sums ----------------
__global__ __launch_bounds__(128) void k_colsum(
    const float* __restrict__ au, const int* __restrict__ cnt,
    float* __restrict__ colsum)
{
  int c  = threadIdx.x;            // 0..127
  int b  = blockIdx.x >> 7;
  int ch = blockIdx.x & 127;
  int f  = c & 63;
  const int*   cp = cnt + ((c >> 6) ? NNODE : 0) + (b<<12);
  const float* ab = au + ((size_t)(b<<12))*64;
  float acc = 0.f;
  int n0 = ch*32;
  for (int n = n0; n < n0+32; ++n)
    acc += (float)cp[n] * ab[(size_t)n*64 + f];
  atomicAdd(&colsum[b*128 + c], acc);
}

// ---------------- P0/P1 via MFMA, stored as bf16 ----------------
__global__ __launch_bounds__(256) void k_p01(
    const float* __restrict__ au, const float* __restrict__ colsum,
    const float* __restrict__ Wn2e, const float* __restrict__ bn2e,
    unsigned short* __restrict__ P0, unsigned short* __restrict__ P1)
{
  const int l  = threadIdx.x & 63;
  const int er = l & 15;
  const int g  = l >> 4;
  bf16x8 wt[4][2], wb[4][2];
  #pragma unroll
  for (int t = 0; t < 4; ++t) {
    const int col = t*16 + er;
    #pragma unroll
    for (int kk = 0; kk < 2; ++kk)
      #pragma unroll
      for (int j = 0; j < 8; ++j) {
        const int k = kk*32 + g*8 + j;
        wt[t][kk][j] = (short)f2bf(Wn2e[k*64 + col]);
        wb[t][kk][j] = (short)f2bf(Wn2e[(64 + k)*64 + col]);
      }
  }
  float bias[4];
  #pragma unroll
  for (int t = 0; t < 4; ++t) bias[t] = bn2e[t*16 + er];

  const int wid = (blockIdx.x*256 + threadIdx.x) >> 6;
  const int nw  = gridDim.x * 4;
  for (int tile = wid; tile < NNODE/16; tile += nw) {
    const int n0 = tile*16;
    const int b  = tile >> 8;
    const float* ar_ = au + (size_t)(n0 + er)*64;
    bf16x8 x0[2], x1[2];
    #pragma unroll
    for (int kk = 0; kk < 2; ++kk) {
      const int f0 = kk*32 + g*8;
      float4 a0 = *(const float4*)(ar_ + f0);
      float4 a1 = *(const float4*)(ar_ + f0 + 4);
      float4 c0 = *(const float4*)(colsum + b*128 + f0);
      float4 c1 = *(const float4*)(colsum + b*128 + f0 + 4);
      float4 d0 = *(const float4*)(colsum + b*128 + 64 + f0);
      float4 d1 = *(const float4*)(colsum + b*128 + 64 + f0 + 4);
      float v[8] = {a0.x,a0.y,a0.z,a0.w,a1.x,a1.y,a1.z,a1.w};
      float c[8] = {c0.x,c0.y,c0.z,c0.w,c1.x,c1.y,c1.z,c1.w};
      float d[8] = {d0.x,d0.y,d0.z,d0.w,d1.x,d1.y,d1.z,d1.w};
      #pragma unroll
      for (int j = 0; j < 8; ++j) {
        x0[kk][j] = (short)f2bf(v[j] * __builtin_amdgcn_rcpf(fmaxf(c[j], 1e-12f)));
        x1[kk][j] = (short)f2bf(v[j] * __builtin_amdgcn_rcpf(fmaxf(d[j], 1e-12f)));
      }
    }
    f32x4 p0[4], p1[4];
    #pragma unroll
    for (int t = 0; t < 4; ++t) {
      p0[t][0]=bias[t]; p0[t][1]=bias[t]; p0[t][2]=bias[t]; p0[t][3]=bias[t];
      p1[t][0]=0.f; p1[t][1]=0.f; p1[t][2]=0.f; p1[t][3]=0.f;
      p0[t] = __builtin_amdgcn_mfma_f32_16x16x32_bf16(x0[0], wt[t][0], p0[t], 0,0,0);
      p0[t] = __builtin_amdgcn_mfma_f32_16x16x32_bf16(x0[1], wt[t][1], p0[t], 0,0,0);
      p1[t] = __builtin_amdgcn_mfma_f32_16x16x32_bf16(x1[0], wb[t][0], p1[t], 0,0,0);
      p1[t] = __builtin_amdgcn_mfma_f32_16x16x32_bf16(x1[1], wb[t][1], p1[t], 0,0,0);
    }
    #pragma unroll
    for (int t = 0; t < 4; ++t)
      #pragma unroll
      for (int r = 0; r < 4; ++r) {
        P0[(size_t)(n0 + g*4 + r)*64 + t*16 + er] = f2bf(p0[t][r]);
        P1[(size_t)(n0 + g*4 + r)*64 + t*16 + er] = f2bf(p1[t][r]);
      }
  }
}

// ---------------- per-edge via MFMA: bf16 bond + bf16 P gathers + LDS-transposed NT stores ----------------
__global__ __launch_bounds__(256) void k_edge_mfma(
    const unsigned short* __restrict__ bondh, const int* __restrict__ tup,
    const unsigned short* __restrict__ P0, const unsigned short* __restrict__ P1,
    const float* __restrict__ We, const float* __restrict__ be,
    float* __restrict__ outB)
{
  __shared__ float st[4][16*65];   // per-wave 16x64 tile, stride 65
  const int l  = threadIdx.x & 63;
  const int er = l & 15;
  const int g  = l >> 4;
  float* myst = st[threadIdx.x >> 6];

  bf16x8 wh[4][2];
  #pragma unroll
  for (int t = 0; t < 4; ++t)
    #pragma unroll
    for (int kk = 0; kk < 2; ++kk)
      #pragma unroll
      for (int j = 0; j < 8; ++j)
        wh[t][kk][j] = (short)f2bf(We[(kk*32 + g*8 + j)*64 + t*16 + er]);
  float bias[4];
  #pragma unroll
  for (int t = 0; t < 4; ++t) bias[t] = be[t*16 + er];

  const int nw  = gridDim.x * 4;
  const int ntiles = NEDGE/16;
  int tile = (blockIdx.x*256 + threadIdx.x) >> 6;
  if (tile >= ntiles) return;
  int2 tt = *(const int2*)(tup + (size_t)(tile*16 + er)*2);
  while (tile < ntiles) {
    const int next = tile + nw;
    int2 ttn = tt;
    if (next < ntiles) ttn = *(const int2*)(tup + (size_t)(next*16 + er)*2);

    const int e0 = tile*16;
    const int b  = e0 >> 17;
    const unsigned short* p0r = P0 + ((size_t)((b<<12) + tt.x))*64;
    const unsigned short* p1r = P1 + ((size_t)((b<<12) + tt.y))*64;
    const unsigned short* br  = bondh + (size_t)(e0 + er)*64;

    bf16x8 ah[2];
    #pragma unroll
    for (int kk = 0; kk < 2; ++kk) {
      const int f0 = kk*32 + g*8;
      bf16x8 bv = *(const bf16x8*)(br + f0);
      bf16x8 q  = *(const bf16x8*)(p0r + f0);
      bf16x8 r  = *(const bf16x8*)(p1r + f0);
      #pragma unroll
      for (int j = 0; j < 8; ++j) {
        float p = bf2f((unsigned short)q[j]) + bf2f((unsigned short)r[j]);
        ah[kk][j] = (short)f2bf(bf2f((unsigned short)bv[j]) + tanh_fast(p));
      }
    }

    f32x4 acc[4];
    #pragma unroll
    for (int t = 0; t < 4; ++t) {
      acc[t][0]=bias[t]; acc[t][1]=bias[t]; acc[t][2]=bias[t]; acc[t][3]=bias[t];
      acc[t] = __builtin_amdgcn_mfma_f32_16x16x32_bf16(ah[0], wh[t][0], acc[t], 0,0,0);
      acc[t] = __builtin_amdgcn_mfma_f32_16x16x32_bf16(ah[1], wh[t][1], acc[t], 0,0,0);
    }

    // transpose D-fragments through LDS (same-wave: no barrier; lgkmcnt orders)
    #pragma unroll
    for (int t = 0; t < 4; ++t)
      #pragma unroll
      for (int r = 0; r < 4; ++r)
        myst[(g*4 + r)*65 + t*16 + er] = acc[t][r];

    f32x4* orow4 = (f32x4*)(outB + (size_t)e0*64);
    #pragma unroll
    for (int i = 0; i < 4; ++i) {
      int idx = i*64 + l;                       // f32x4 index in the 16x64 tile
      f32x4 v = *(const f32x4*)&myst[(idx >> 4)*65 + (idx & 15)*4];
      __builtin_nontemporal_store(v, orow4 + idx);   // 1 KB contiguous per instr
    }

    tile = next; tt = ttn;
  }
}

extern "C" void kernel_launch(void* const* d_in, const int* in_sizes, int n_in,
                              void* d_out, int out_size, void* d_ws, size_t ws_size,
                              hipStream_t stream)
{
  (void)in_sizes; (void)n_in; (void)out_size; (void)ws_size;
  const float* atom = (const float*)d_in[0];
  const float* bond = (const float*)d_in[1];
  const int*   adj  = (const int*)d_in[2];
  const int*   tup  = (const int*)d_in[3];
  const float* Wn   = (const float*)d_in[4];
  const float* We   = (const float*)d_in[5];
  const float* Wn2e = (const float*)d_in[6];
  const float* bn   = (const float*)d_in[7];
  const float* be   = (const float*)d_in[8];
  const float* bn2e = (const float*)d_in[9];

  float* au   = (float*)d_out;             // output 0: (B,N,64)
  float* outB = (float*)d_out + AU_SIZE;   // output 1: (B,N,M,64)

  char* ws = (char*)d_ws;
  int*            cnt    = (int*)ws;                         // @0       128 KB
  float*          colsum = (float*)(ws + 0x20000);           // @128K    2 KB
  float*          inv    = (float*)(ws + 0x40000);           // @256K    2 MB
  unsigned short* P0     = (unsigned short*)(ws + 0x240000); // @2.25M   2 MB
  unsigned short* P1     = (unsigned short*)(ws + 0x440000); // @4.25M   2 MB
  int*            part   = (int*)(ws + 0x640000);            // @6.25M   2 MB
  unsigned short* bondh  = (unsigned short*)(ws + 0x1000000);// @16M     64 MB

  hipLaunchKernelGGL(k_norm,      dim3(2048),     dim3(256), 0, stream, bond, inv, bondh);
  hipLaunchKernelGGL(k_hist_lds,  dim3(64),       dim3(256), 0, stream, tup, part);
  hipLaunchKernelGGL(k_histsum,   dim3(128),      dim3(256), 0, stream, part, cnt, colsum);
  hipLaunchKernelGGL(k_node,      dim3(NNODE/16), dim3(256), 0, stream, atom, inv, adj, Wn, bn, au);
  hipLaunchKernelGGL(k_colsum,    dim3(BB*128),   dim3(128), 0, stream, au, cnt, colsum);
  hipLaunchKernelGGL(k_p01,       dim3(256),      dim3(256), 0, stream, au, colsum, Wn2e, bn2e, P0, P1);
  hipLaunchKernelGGL(k_edge_mfma, dim3(2048),     dim3(256), 0, stream, bondh, tup, P0, P1, We, be, outB);
}